// Round 15
// baseline (183.103 us; speedup 1.0000x reference)
//
#include <hip/hip_runtime.h>
#include <math.h>

#define NN 50000
#define EE 800000
#define TOT (EE + NN)          // 850000 edges incl. self loops
#define CC 128
#define HH 4
#define HCW 512                // H*C
#define SCAN_B 196             // ceil(NN/256)
#define RB 64                  // rows per gemm block
#define GEMB ((NN + RB - 1) / RB)        // 782 gemm blocks
#define CNTB ((TOT + 1023) / 1024)       // 831 count blocks
#define LOG2E 1.442695040888963f

typedef short s16x8 __attribute__((ext_vector_type(8)));
typedef float f32x4 __attribute__((ext_vector_type(4)));
typedef float f32x2 __attribute__((ext_vector_type(2)));

// fp32 -> bf16 bits, round-to-nearest-even
__device__ __forceinline__ unsigned f2bf(float f) {
    unsigned u = __float_as_uint(f);
    return (u + 0x7fffu + ((u >> 16) & 1u)) >> 16;
}

// -------- P2: W [128][512] fp32 -> Wt [512][128] bf16 --------
__global__ __launch_bounds__(256) void k_prep_w(
    const float* __restrict__ W, unsigned short* __restrict__ wt)
{
    const int i = blockIdx.x * 256 + threadIdx.x;   // i = c*128 + k
    if (i >= HCW * CC) return;
    const int c = i >> 7, k = i & 127;
    wt[i] = (unsigned short)f2bf(W[(size_t)k * HCW + c]);
}

// -------- K1 (fat): blocks [0,CNTB) = degree count (FIRST: atomic-fabric
// bound, overlaps under the gemm blocks that follow);
// blocks [CNTB, CNTB+GEMB) = MFMA gemm -> fp8 xh + fused att --------
__global__ __launch_bounds__(1024, 4) void k_fat(
    const float* __restrict__ x,             // [NN][128] fp32
    const unsigned short* __restrict__ wt,   // [512][128] bf16 = W^T
    const float* __restrict__ att_s, const float* __restrict__ att_d,
    const int* __restrict__ ei,
    unsigned char* __restrict__ xhq,         // [NN][512] fp8 e4m3
    float* __restrict__ asrc, float* __restrict__ adst,
    int* __restrict__ deg, unsigned short* __restrict__ pos)
{
    __shared__ unsigned short xs[RB][CC + 8];   // 64x136 bf16
    __shared__ float red[16][2][4][16];         // [wave][src/dst][rt][row]

    if (blockIdx.x < CNTB) {
        // ---- degree count part (dispatched first, stalls on atomics while
        //      the gemm blocks behind it use the VALU/MFMA pipes) ----
        const int e = blockIdx.x * 1024 + threadIdx.x;
        if (e < TOT) {
            const int d = (e < EE) ? ei[EE + e] : (e - EE);
            pos[e] = (unsigned short)atomicAdd(deg + d, 1);
        }
        return;
    }

    // ---- gemm part ----
    const int r0   = (blockIdx.x - CNTB) * RB;
    const int wv   = threadIdx.x >> 6;       // 0..15
    const int lane = threadIdx.x & 63;
    const int lrow = lane & 15;
    const int kg   = lane >> 4;
    const int n_base = wv * 32;              // 32 channels per wave
    const int h    = wv >> 2;                // head = n_base / 128

    // stage 64 rows of x as bf16 into LDS
    for (int i = threadIdx.x; i < RB * 32; i += 1024) {
        const int row = i >> 5;
        const int c4  = (i & 31) * 4;
        const int grow = r0 + row;
        float4 v = make_float4(0.f, 0.f, 0.f, 0.f);
        if (grow < NN) v = *(const float4*)(x + (size_t)grow * CC + c4);
        uint2 o;
        o.x = f2bf(v.x) | (f2bf(v.y) << 16);
        o.y = f2bf(v.z) | (f2bf(v.w) << 16);
        *(uint2*)(&xs[row][c4]) = o;
    }

    // this wave's 8 wt fragments (2 channel-tiles x 4 k-chunks) stay in VGPRs
    s16x8 wf0[4], wf1[4];
#pragma unroll
    for (int kk = 0; kk < 4; ++kk) {
        wf0[kk] = *(const s16x8*)(wt + (size_t)(n_base + 0  + lrow) * CC + kg * 8 + kk * 32);
        wf1[kk] = *(const s16x8*)(wt + (size_t)(n_base + 16 + lrow) * CC + kg * 8 + kk * 32);
    }
    __syncthreads();

    const int cbase = h * CC + (wv & 3) * 32 + kg * 4;   // channel within head

    float psr[4], pdr[4];

    for (int rt = 0; rt < 4; ++rt) {
        f32x4 acc0 = {0.f, 0.f, 0.f, 0.f};
        f32x4 acc1 = {0.f, 0.f, 0.f, 0.f};
#pragma unroll
        for (int kk = 0; kk < 4; ++kk) {
            const s16x8 b = *(const s16x8*)(&xs[rt * 16 + lrow][kg * 8 + kk * 32]);
            acc0 = __builtin_amdgcn_mfma_f32_16x16x32_bf16(wf0[kk], b, acc0, 0, 0, 0);
            acc1 = __builtin_amdgcn_mfma_f32_16x16x32_bf16(wf1[kk], b, acc1, 0, 0, 0);
        }

        const int grow = r0 + rt * 16 + lrow;
        if (grow < NN) {
            unsigned char* orow = xhq + (size_t)grow * HCW + n_base + kg * 4;
            unsigned u;
            u = __builtin_amdgcn_cvt_pk_fp8_f32(acc0[0], acc0[1], 0u, false);
            u = __builtin_amdgcn_cvt_pk_fp8_f32(acc0[2], acc0[3], u, true);
            *(unsigned*)(orow) = u;
            u = __builtin_amdgcn_cvt_pk_fp8_f32(acc1[0], acc1[1], 0u, false);
            u = __builtin_amdgcn_cvt_pk_fp8_f32(acc1[2], acc1[3], u, true);
            *(unsigned*)(orow + 16) = u;
        }

        // fused a_src/a_dst epilogue (coeffs loaded in-loop: short live range)
        float ps, pd;
        {
            const float4 c0 = *(const float4*)(att_s + cbase);
            const float4 c1 = *(const float4*)(att_s + cbase + 16);
            ps = acc0[0]*c0.x + acc0[1]*c0.y + acc0[2]*c0.z + acc0[3]*c0.w
               + acc1[0]*c1.x + acc1[1]*c1.y + acc1[2]*c1.z + acc1[3]*c1.w;
        }
        {
            const float4 c0 = *(const float4*)(att_d + cbase);
            const float4 c1 = *(const float4*)(att_d + cbase + 16);
            pd = acc0[0]*c0.x + acc0[1]*c0.y + acc0[2]*c0.z + acc0[3]*c0.w
               + acc1[0]*c1.x + acc1[1]*c1.y + acc1[2]*c1.z + acc1[3]*c1.w;
        }
        ps += __shfl_xor(ps, 16); ps += __shfl_xor(ps, 32);
        pd += __shfl_xor(pd, 16); pd += __shfl_xor(pd, 32);
        psr[rt] = ps;
        pdr[rt] = pd;
    }

#pragma unroll
    for (int rt = 0; rt < 4; ++rt) {
        red[wv][0][rt][lrow] = psr[rt];   // kg groups write identical values
        red[wv][1][rt][lrow] = pdr[rt];
    }
    __syncthreads();                      // single barrier for the epilogue
    if (threadIdx.x < 512) {
        const int t     = threadIdx.x & 15;
        const int rt    = (threadIdx.x >> 4) & 3;
        const int hh    = (threadIdx.x >> 6) & 3;
        const int which = (threadIdx.x >> 8) & 1;    // 0 = src, 1 = dst
        const int row   = r0 + rt * 16 + t;
        if (row < NN) {
            const float v = red[hh * 4 + 0][which][rt][t] + red[hh * 4 + 1][which][rt][t]
                          + red[hh * 4 + 2][which][rt][t] + red[hh * 4 + 3][which][rt][t];
            float* dst = which ? adst : asrc;
            dst[row * HH + hh] = v * LOG2E;   // pre-scale for exp2 in gather
        }
    }
}

// -------- scan: per-block partial sums --------
__global__ __launch_bounds__(256) void s_part(
    const int* __restrict__ deg, int* __restrict__ part)
{
    const int idx = blockIdx.x * 256 + threadIdx.x;
    int v = (idx < NN) ? deg[idx] : 0;
#pragma unroll
    for (int off = 1; off < 64; off <<= 1) v += __shfl_xor(v, off);
    __shared__ int sm[4];
    if ((threadIdx.x & 63) == 0) sm[threadIdx.x >> 6] = v;
    __syncthreads();
    if (threadIdx.x == 0) part[blockIdx.x] = sm[0] + sm[1] + sm[2] + sm[3];
}

// -------- scan apply (mid-scan inlined) --------
__global__ __launch_bounds__(256) void s_apply(
    const int* __restrict__ deg, const int* __restrict__ part,
    int* __restrict__ rowptr)
{
    __shared__ int sm[256];
    __shared__ int ws[4];
    const int t   = threadIdx.x;
    const int bid = blockIdx.x;

    int pv = (t < SCAN_B && t < bid) ? part[t] : 0;
#pragma unroll
    for (int off = 1; off < 64; off <<= 1) pv += __shfl_xor(pv, off);
    if ((t & 63) == 0) ws[t >> 6] = pv;
    __syncthreads();
    const int poff = ws[0] + ws[1] + ws[2] + ws[3];

    const int idx = bid * 256 + t;
    const int v = (idx < NN) ? deg[idx] : 0;
    sm[t] = v;
    __syncthreads();
    for (int off = 1; off < 256; off <<= 1) {
        int u = (t >= off) ? sm[t - off] : 0;
        __syncthreads();
        sm[t] += u;
        __syncthreads();
    }
    if (idx < NN) rowptr[idx] = poff + sm[t] - v;   // exclusive
    if (bid == 0 && t == 0) rowptr[NN] = TOT;
}

// -------- K4: atomic-free scatter of src ids into dst-sorted CSR --------
__global__ __launch_bounds__(256) void k_scatter(
    const int* __restrict__ ei, const int* __restrict__ rowptr,
    const unsigned short* __restrict__ pos, int* __restrict__ csr_s)
{
    const int e = blockIdx.x * 256 + threadIdx.x;
    if (e >= TOT) return;
    int s, d;
    if (e < EE) { s = ei[e]; d = ei[EE + e]; } else { s = d = e - EE; }
    csr_s[rowptr[d] + pos[e]] = s;
}

// -------- K5: single-pass softmax + fp8 gather + residual --------
// one wave per node; lane = h*16 + t owns channels lane*8..+7.
// Edge ids wave-uniform -> SGPR; asrc rows read as uniform float4
// (scalar pipe) and selected per-lane by head via cndmask.
// Main loop 16-deep (latency-bound: ~1 stall window per node).
__global__ __launch_bounds__(256) void k_gather(
    const int* __restrict__ rowptr, const int* __restrict__ csr_s,
    const float* __restrict__ asrc, const float* __restrict__ adst,
    const unsigned char* __restrict__ xhq, const float* __restrict__ x,
    const float* __restrict__ bias, float* __restrict__ out)
{
    const int gtid = blockIdx.x * 256 + threadIdx.x;
    const int n    = __builtin_amdgcn_readfirstlane(gtid >> 6);   // wave-uniform
    const int lane = threadIdx.x & 63;
    if (n >= NN) return;
    const int h = lane >> 4;
    const int t = lane & 15;
    const bool hb0 = (h & 1) != 0;
    const bool hb1 = (h & 2) != 0;

    const int beg = __builtin_amdgcn_readfirstlane(rowptr[n]);
    const int end = __builtin_amdgcn_readfirstlane(rowptr[n + 1]);
    const float ad = adst[n * HH + h];
    const int voff = lane << 3;            // byte offset within a 512B xh row
    const float4* asrc4 = (const float4*)asrc;

    float ssum = 0.f;
    f32x2 a0 = {0.f, 0.f}, a1 = {0.f, 0.f}, a2 = {0.f, 0.f}, a3 = {0.f, 0.f};

    int j = beg;
    // ---- exact 16-wide batches, scalar bases ----
    for (; j + 16 <= end; j += 16) {
        int ss[16];
#pragma unroll
        for (int u = 0; u < 16; ++u)
            ss[u] = __builtin_amdgcn_readfirstlane(csr_s[j + u]);
        uint2 qq[16];
#pragma unroll
        for (int u = 0; u < 16; ++u)
            qq[u] = *(const uint2*)(xhq + ((size_t)(unsigned)ss[u] << 9) + voff);
        float ww[16];
#pragma unroll
        for (int u = 0; u < 16; ++u) {
            const float4 av = asrc4[ss[u]];            // uniform -> s_load
            float e = hb1 ? (hb0 ? av.w : av.z) : (hb0 ? av.y : av.x);
            e += ad;
            e = fmaxf(e, 0.2f * e);                    // leaky_relu, exact
            ww[u] = exp2f(e);
            ssum += ww[u];
        }
#pragma unroll
        for (int u = 0; u < 16; ++u) {
            const f32x2 p0 = __builtin_amdgcn_cvt_pk_f32_fp8(qq[u].x, false);
            const f32x2 p1 = __builtin_amdgcn_cvt_pk_f32_fp8(qq[u].x, true);
            const f32x2 p2 = __builtin_amdgcn_cvt_pk_f32_fp8(qq[u].y, false);
            const f32x2 p3 = __builtin_amdgcn_cvt_pk_f32_fp8(qq[u].y, true);
            const f32x2 wv = {ww[u], ww[u]};
            a0 += wv * p0; a1 += wv * p1; a2 += wv * p2; a3 += wv * p3;
        }
    }
    // ---- tail: predicated 4-wide batches (indices still uniform) ----
    for (int base = j; base < end; base += 4) {
        int ss[4];
#pragma unroll
        for (int u = 0; u < 4; ++u) {
            const int idx = (base + u < end) ? (base + u) : (end - 1);
            ss[u] = __builtin_amdgcn_readfirstlane(csr_s[idx]);
        }
        uint2 qq[4];
#pragma unroll
        for (int u = 0; u < 4; ++u)
            qq[u] = *(const uint2*)(xhq + ((size_t)(unsigned)ss[u] << 9) + voff);
        float ww[4];
#pragma unroll
        for (int u = 0; u < 4; ++u) {
            const float4 av = asrc4[ss[u]];
            float e = hb1 ? (hb0 ? av.w : av.z) : (hb0 ? av.y : av.x);
            e += ad;
            e = fmaxf(e, 0.2f * e);
            float w = exp2f(e);
            w = (base + u < end) ? w : 0.f;
            ww[u] = w;
            ssum += w;
        }
#pragma unroll
        for (int u = 0; u < 4; ++u) {
            const f32x2 p0 = __builtin_amdgcn_cvt_pk_f32_fp8(qq[u].x, false);
            const f32x2 p1 = __builtin_amdgcn_cvt_pk_f32_fp8(qq[u].x, true);
            const f32x2 p2 = __builtin_amdgcn_cvt_pk_f32_fp8(qq[u].y, false);
            const f32x2 p3 = __builtin_amdgcn_cvt_pk_f32_fp8(qq[u].y, true);
            const f32x2 wv = {ww[u], ww[u]};
            a0 += wv * p0; a1 += wv * p1; a2 += wv * p2; a3 += wv * p3;
        }
    }

    const float inv = 0.25f / (ssum + 1e-16f);
    const f32x2 iv = {inv, inv};
    a0 *= iv; a1 *= iv; a2 *= iv; a3 *= iv;
    float r0 = a0.x, r1 = a0.y, r2 = a1.x, r3 = a1.y;
    float r4 = a2.x, r5 = a2.y, r6 = a3.x, r7 = a3.y;

    // sum across the 4 head groups (lane bits 4..5)
#pragma unroll
    for (int off = 16; off < 64; off <<= 1) {
        r0 += __shfl_xor(r0, off); r1 += __shfl_xor(r1, off);
        r2 += __shfl_xor(r2, off); r3 += __shfl_xor(r3, off);
        r4 += __shfl_xor(r4, off); r5 += __shfl_xor(r5, off);
        r6 += __shfl_xor(r6, off); r7 += __shfl_xor(r7, off);
    }

    if (h == 0) {
        const int c = t * 8;
        const float4 x0 = *(const float4*)(x + (size_t)n * CC + c);
        const float4 x1 = *(const float4*)(x + (size_t)n * CC + c + 4);
        const float4 b0 = *(const float4*)(bias + c);
        const float4 b1 = *(const float4*)(bias + c + 4);
        float4 o0, o1;
        o0.x = 0.8f * x0.x + 0.2f * (r0 + b0.x);
        o0.y = 0.8f * x0.y + 0.2f * (r1 + b0.y);
        o0.z = 0.8f * x0.z + 0.2f * (r2 + b0.z);
        o0.w = 0.8f * x0.w + 0.2f * (r3 + b0.w);
        o1.x = 0.8f * x1.x + 0.2f * (r4 + b1.x);
        o1.y = 0.8f * x1.y + 0.2f * (r5 + b1.y);
        o1.z = 0.8f * x1.z + 0.2f * (r6 + b1.z);
        o1.w = 0.8f * x1.w + 0.2f * (r7 + b1.w);
        *(float4*)(out + (size_t)n * CC + c)     = o0;
        *(float4*)(out + (size_t)n * CC + c + 4) = o1;
    }
}

extern "C" void kernel_launch(void* const* d_in, const int* in_sizes, int n_in,
                              void* d_out, int out_size, void* d_ws, size_t ws_size,
                              hipStream_t stream)
{
    const float* x     = (const float*)d_in[0];
    const int*   ei    = (const int*)d_in[1];
    const float* W     = (const float*)d_in[2];
    const float* att_s = (const float*)d_in[3];
    const float* att_d = (const float*)d_in[4];
    const float* bias  = (const float*)d_in[5];
    float* out = (float*)d_out;

    char* p = (char*)d_ws;
    unsigned char*  xhq   = (unsigned char*)p;  p += (size_t)NN * HCW;      // 25.6 MB
    unsigned short* wt    = (unsigned short*)p; p += (size_t)HCW * CC * 2;  // 128 KB
    float*          asrc  = (float*)p;          p += (size_t)NN * HH * 4;
    float*          adst  = (float*)p;          p += (size_t)NN * HH * 4;
    int*            deg   = (int*)p;            p += (size_t)NN * 4;        // zeroed
    unsigned short* pos   = (unsigned short*)p; p += (size_t)TOT * 2;
    int*            rowptr= (int*)p;            p += (size_t)(NN + 1) * 4;
    int*            csr_s = (int*)p;            p += (size_t)TOT * 4;
    int*            part  = (int*)p;            p += (size_t)SCAN_B * 4;

    hipMemsetAsync(deg, 0, (size_t)NN * 4, stream);

    k_prep_w<<<(HCW * CC + 255) / 256, 256, 0, stream>>>(W, wt);
    k_fat<<<CNTB + GEMB, 1024, 0, stream>>>(x, wt, att_s, att_d, ei, xhq, asrc, adst, deg, pos);
    s_part<<<SCAN_B, 256, 0, stream>>>(deg, part);
    s_apply<<<SCAN_B, 256, 0, stream>>>(deg, part, rowptr);
    k_scatter<<<(TOT + 255) / 256, 256, 0, stream>>>(ei, rowptr, pos, csr_s);
    {
        const long long threads = (long long)NN * 64;
        const int blocks = (int)((threads + 255) / 256);
        k_gather<<<blocks, 256, 0, stream>>>(rowptr, csr_s, asrc, adst, xhq, x, bias, out);
    }
}

// Round 16
// 164.871 us; speedup vs baseline: 1.1106x; 1.1106x over previous
//
#include <hip/hip_runtime.h>
#include <math.h>

#define NN 50000
#define EE 800000
#define TOT (EE + NN)          // 850000 edges incl. self loops
#define CC 128
#define HH 4
#define HCW 512                // H*C
#define SCAN_B 196             // ceil(NN/256)
#define RB 64                  // rows per gemm block
#define GEMB ((NN + RB - 1) / RB)        // 782 gemm blocks
#define CNTB ((TOT + 1023) / 1024)       // 831 count blocks
#define LOG2E 1.442695040888963f

typedef short s16x8 __attribute__((ext_vector_type(8)));
typedef float f32x4 __attribute__((ext_vector_type(4)));
typedef float f32x2 __attribute__((ext_vector_type(2)));

// fp32 -> bf16 bits, round-to-nearest-even
__device__ __forceinline__ unsigned f2bf(float f) {
    unsigned u = __float_as_uint(f);
    return (u + 0x7fffu + ((u >> 16) & 1u)) >> 16;
}

// -------- P2: W [128][512] fp32 -> Wt [512][128] bf16 --------
__global__ __launch_bounds__(256) void k_prep_w(
    const float* __restrict__ W, unsigned short* __restrict__ wt)
{
    const int i = blockIdx.x * 256 + threadIdx.x;   // i = c*128 + k
    if (i >= HCW * CC) return;
    const int c = i >> 7, k = i & 127;
    wt[i] = (unsigned short)f2bf(W[(size_t)k * HCW + c]);
}

// -------- K1 (fat): blocks [0,CNTB) = degree count (FIRST: atomic-fabric
// bound, overlaps under the gemm blocks that follow);
// blocks [CNTB, CNTB+GEMB) = MFMA gemm -> fp8 xh + fused att --------
__global__ __launch_bounds__(1024, 4) void k_fat(
    const float* __restrict__ x,             // [NN][128] fp32
    const unsigned short* __restrict__ wt,   // [512][128] bf16 = W^T
    const float* __restrict__ att_s, const float* __restrict__ att_d,
    const int* __restrict__ ei,
    unsigned char* __restrict__ xhq,         // [NN][512] fp8 e4m3
    float* __restrict__ asrc, float* __restrict__ adst,
    int* __restrict__ deg, unsigned short* __restrict__ pos)
{
    __shared__ unsigned short xs[RB][CC + 8];   // 64x136 bf16
    __shared__ float red[16][2][4][16];         // [wave][src/dst][rt][row]

    if (blockIdx.x < CNTB) {
        // ---- degree count part (dispatched first, stalls on atomics while
        //      the gemm blocks behind it use the VALU/MFMA pipes) ----
        const int e = blockIdx.x * 1024 + threadIdx.x;
        if (e < TOT) {
            const int d = (e < EE) ? ei[EE + e] : (e - EE);
            pos[e] = (unsigned short)atomicAdd(deg + d, 1);
        }
        return;
    }

    // ---- gemm part ----
    const int r0   = (blockIdx.x - CNTB) * RB;
    const int wv   = threadIdx.x >> 6;       // 0..15
    const int lane = threadIdx.x & 63;
    const int lrow = lane & 15;
    const int kg   = lane >> 4;
    const int n_base = wv * 32;              // 32 channels per wave
    const int h    = wv >> 2;                // head = n_base / 128

    // stage 64 rows of x as bf16 into LDS
    for (int i = threadIdx.x; i < RB * 32; i += 1024) {
        const int row = i >> 5;
        const int c4  = (i & 31) * 4;
        const int grow = r0 + row;
        float4 v = make_float4(0.f, 0.f, 0.f, 0.f);
        if (grow < NN) v = *(const float4*)(x + (size_t)grow * CC + c4);
        uint2 o;
        o.x = f2bf(v.x) | (f2bf(v.y) << 16);
        o.y = f2bf(v.z) | (f2bf(v.w) << 16);
        *(uint2*)(&xs[row][c4]) = o;
    }

    // this wave's 8 wt fragments (2 channel-tiles x 4 k-chunks) stay in VGPRs
    s16x8 wf0[4], wf1[4];
#pragma unroll
    for (int kk = 0; kk < 4; ++kk) {
        wf0[kk] = *(const s16x8*)(wt + (size_t)(n_base + 0  + lrow) * CC + kg * 8 + kk * 32);
        wf1[kk] = *(const s16x8*)(wt + (size_t)(n_base + 16 + lrow) * CC + kg * 8 + kk * 32);
    }
    __syncthreads();

    const int cbase = h * CC + (wv & 3) * 32 + kg * 4;   // channel within head

    float psr[4], pdr[4];

    for (int rt = 0; rt < 4; ++rt) {
        f32x4 acc0 = {0.f, 0.f, 0.f, 0.f};
        f32x4 acc1 = {0.f, 0.f, 0.f, 0.f};
#pragma unroll
        for (int kk = 0; kk < 4; ++kk) {
            const s16x8 b = *(const s16x8*)(&xs[rt * 16 + lrow][kg * 8 + kk * 32]);
            acc0 = __builtin_amdgcn_mfma_f32_16x16x32_bf16(wf0[kk], b, acc0, 0, 0, 0);
            acc1 = __builtin_amdgcn_mfma_f32_16x16x32_bf16(wf1[kk], b, acc1, 0, 0, 0);
        }

        const int grow = r0 + rt * 16 + lrow;
        if (grow < NN) {
            unsigned char* orow = xhq + (size_t)grow * HCW + n_base + kg * 4;
            unsigned u;
            u = __builtin_amdgcn_cvt_pk_fp8_f32(acc0[0], acc0[1], 0u, false);
            u = __builtin_amdgcn_cvt_pk_fp8_f32(acc0[2], acc0[3], u, true);
            *(unsigned*)(orow) = u;
            u = __builtin_amdgcn_cvt_pk_fp8_f32(acc1[0], acc1[1], 0u, false);
            u = __builtin_amdgcn_cvt_pk_fp8_f32(acc1[2], acc1[3], u, true);
            *(unsigned*)(orow + 16) = u;
        }

        // fused a_src/a_dst epilogue (coeffs loaded in-loop: short live range)
        float ps, pd;
        {
            const float4 c0 = *(const float4*)(att_s + cbase);
            const float4 c1 = *(const float4*)(att_s + cbase + 16);
            ps = acc0[0]*c0.x + acc0[1]*c0.y + acc0[2]*c0.z + acc0[3]*c0.w
               + acc1[0]*c1.x + acc1[1]*c1.y + acc1[2]*c1.z + acc1[3]*c1.w;
        }
        {
            const float4 c0 = *(const float4*)(att_d + cbase);
            const float4 c1 = *(const float4*)(att_d + cbase + 16);
            pd = acc0[0]*c0.x + acc0[1]*c0.y + acc0[2]*c0.z + acc0[3]*c0.w
               + acc1[0]*c1.x + acc1[1]*c1.y + acc1[2]*c1.z + acc1[3]*c1.w;
        }
        ps += __shfl_xor(ps, 16); ps += __shfl_xor(ps, 32);
        pd += __shfl_xor(pd, 16); pd += __shfl_xor(pd, 32);
        psr[rt] = ps;
        pdr[rt] = pd;
    }

#pragma unroll
    for (int rt = 0; rt < 4; ++rt) {
        red[wv][0][rt][lrow] = psr[rt];   // kg groups write identical values
        red[wv][1][rt][lrow] = pdr[rt];
    }
    __syncthreads();                      // single barrier for the epilogue
    if (threadIdx.x < 512) {
        const int t     = threadIdx.x & 15;
        const int rt    = (threadIdx.x >> 4) & 3;
        const int hh    = (threadIdx.x >> 6) & 3;
        const int which = (threadIdx.x >> 8) & 1;    // 0 = src, 1 = dst
        const int row   = r0 + rt * 16 + t;
        if (row < NN) {
            const float v = red[hh * 4 + 0][which][rt][t] + red[hh * 4 + 1][which][rt][t]
                          + red[hh * 4 + 2][which][rt][t] + red[hh * 4 + 3][which][rt][t];
            float* dst = which ? adst : asrc;
            dst[row * HH + hh] = v * LOG2E;   // pre-scale for exp2 in gather
        }
    }
}

// -------- scan: per-block partial sums --------
__global__ __launch_bounds__(256) void s_part(
    const int* __restrict__ deg, int* __restrict__ part)
{
    const int idx = blockIdx.x * 256 + threadIdx.x;
    int v = (idx < NN) ? deg[idx] : 0;
#pragma unroll
    for (int off = 1; off < 64; off <<= 1) v += __shfl_xor(v, off);
    __shared__ int sm[4];
    if ((threadIdx.x & 63) == 0) sm[threadIdx.x >> 6] = v;
    __syncthreads();
    if (threadIdx.x == 0) part[blockIdx.x] = sm[0] + sm[1] + sm[2] + sm[3];
}

// -------- scan apply (mid-scan inlined) --------
__global__ __launch_bounds__(256) void s_apply(
    const int* __restrict__ deg, const int* __restrict__ part,
    int* __restrict__ rowptr)
{
    __shared__ int sm[256];
    __shared__ int ws[4];
    const int t   = threadIdx.x;
    const int bid = blockIdx.x;

    int pv = (t < SCAN_B && t < bid) ? part[t] : 0;
#pragma unroll
    for (int off = 1; off < 64; off <<= 1) pv += __shfl_xor(pv, off);
    if ((t & 63) == 0) ws[t >> 6] = pv;
    __syncthreads();
    const int poff = ws[0] + ws[1] + ws[2] + ws[3];

    const int idx = bid * 256 + t;
    const int v = (idx < NN) ? deg[idx] : 0;
    sm[t] = v;
    __syncthreads();
    for (int off = 1; off < 256; off <<= 1) {
        int u = (t >= off) ? sm[t - off] : 0;
        __syncthreads();
        sm[t] += u;
        __syncthreads();
    }
    if (idx < NN) rowptr[idx] = poff + sm[t] - v;   // exclusive
    if (bid == 0 && t == 0) rowptr[NN] = TOT;
}

// -------- K4: atomic-free scatter of src ids into dst-sorted CSR --------
__global__ __launch_bounds__(256) void k_scatter(
    const int* __restrict__ ei, const int* __restrict__ rowptr,
    const unsigned short* __restrict__ pos, int* __restrict__ csr_s)
{
    const int e = blockIdx.x * 256 + threadIdx.x;
    if (e >= TOT) return;
    int s, d;
    if (e < EE) { s = ei[e]; d = ei[EE + e]; } else { s = d = e - EE; }
    csr_s[rowptr[d] + pos[e]] = s;
}

// -------- K5: single-pass softmax + fp8 gather + residual (r13 shape) ----
// one wave per node; lane = h*16 + t owns channels lane*8..+7.
// Edge ids / row bases wave-uniform -> readfirstlane to SGPR; per-lane
// asrc dword load; 8-deep main loop; predicated 4-wide tail.
__global__ __launch_bounds__(256) void k_gather(
    const int* __restrict__ rowptr, const int* __restrict__ csr_s,
    const float* __restrict__ asrc, const float* __restrict__ adst,
    const unsigned char* __restrict__ xhq, const float* __restrict__ x,
    const float* __restrict__ bias, float* __restrict__ out)
{
    const int gtid = blockIdx.x * 256 + threadIdx.x;
    const int n    = __builtin_amdgcn_readfirstlane(gtid >> 6);   // wave-uniform
    const int lane = threadIdx.x & 63;
    if (n >= NN) return;
    const int h = lane >> 4;
    const int t = lane & 15;

    const int beg = __builtin_amdgcn_readfirstlane(rowptr[n]);
    const int end = __builtin_amdgcn_readfirstlane(rowptr[n + 1]);
    const float ad = adst[n * HH + h];
    const int voff = lane << 3;            // byte offset within a 512B xh row

    float ssum = 0.f;
    f32x2 a0 = {0.f, 0.f}, a1 = {0.f, 0.f}, a2 = {0.f, 0.f}, a3 = {0.f, 0.f};

    int j = beg;
    // ---- exact 8-wide batches, scalar bases ----
    for (; j + 8 <= end; j += 8) {
        int ss[8];
#pragma unroll
        for (int u = 0; u < 8; ++u)
            ss[u] = __builtin_amdgcn_readfirstlane(csr_s[j + u]);
        uint2 qq[8];
#pragma unroll
        for (int u = 0; u < 8; ++u)
            qq[u] = *(const uint2*)(xhq + ((size_t)(unsigned)ss[u] << 9) + voff);
        float ww[8];
#pragma unroll
        for (int u = 0; u < 8; ++u) {
            float e = asrc[(ss[u] << 2) + h] + ad;
            e = fmaxf(e, 0.2f * e);        // leaky_relu, exact
            ww[u] = exp2f(e);
            ssum += ww[u];
        }
#pragma unroll
        for (int u = 0; u < 8; ++u) {
            const f32x2 p0 = __builtin_amdgcn_cvt_pk_f32_fp8(qq[u].x, false);
            const f32x2 p1 = __builtin_amdgcn_cvt_pk_f32_fp8(qq[u].x, true);
            const f32x2 p2 = __builtin_amdgcn_cvt_pk_f32_fp8(qq[u].y, false);
            const f32x2 p3 = __builtin_amdgcn_cvt_pk_f32_fp8(qq[u].y, true);
            const f32x2 wv = {ww[u], ww[u]};
            a0 += wv * p0; a1 += wv * p1; a2 += wv * p2; a3 += wv * p3;
        }
    }
    // ---- tail: up to two predicated 4-wide batches (indices still uniform) --
    for (int base = j; base < end; base += 4) {
        int ss[4];
#pragma unroll
        for (int u = 0; u < 4; ++u) {
            const int idx = (base + u < end) ? (base + u) : (end - 1);
            ss[u] = __builtin_amdgcn_readfirstlane(csr_s[idx]);
        }
        uint2 qq[4];
#pragma unroll
        for (int u = 0; u < 4; ++u)
            qq[u] = *(const uint2*)(xhq + ((size_t)(unsigned)ss[u] << 9) + voff);
        float ww[4];
#pragma unroll
        for (int u = 0; u < 4; ++u) {
            float e = asrc[(ss[u] << 2) + h] + ad;
            e = fmaxf(e, 0.2f * e);
            float w = exp2f(e);
            w = (base + u < end) ? w : 0.f;
            ww[u] = w;
            ssum += w;
        }
#pragma unroll
        for (int u = 0; u < 4; ++u) {
            const f32x2 p0 = __builtin_amdgcn_cvt_pk_f32_fp8(qq[u].x, false);
            const f32x2 p1 = __builtin_amdgcn_cvt_pk_f32_fp8(qq[u].x, true);
            const f32x2 p2 = __builtin_amdgcn_cvt_pk_f32_fp8(qq[u].y, false);
            const f32x2 p3 = __builtin_amdgcn_cvt_pk_f32_fp8(qq[u].y, true);
            const f32x2 wv = {ww[u], ww[u]};
            a0 += wv * p0; a1 += wv * p1; a2 += wv * p2; a3 += wv * p3;
        }
    }

    const float inv = 0.25f / (ssum + 1e-16f);
    const f32x2 iv = {inv, inv};
    a0 *= iv; a1 *= iv; a2 *= iv; a3 *= iv;
    float r0 = a0.x, r1 = a0.y, r2 = a1.x, r3 = a1.y;
    float r4 = a2.x, r5 = a2.y, r6 = a3.x, r7 = a3.y;

    // sum across the 4 head groups (lane bits 4..5)
#pragma unroll
    for (int off = 16; off < 64; off <<= 1) {
        r0 += __shfl_xor(r0, off); r1 += __shfl_xor(r1, off);
        r2 += __shfl_xor(r2, off); r3 += __shfl_xor(r3, off);
        r4 += __shfl_xor(r4, off); r5 += __shfl_xor(r5, off);
        r6 += __shfl_xor(r6, off); r7 += __shfl_xor(r7, off);
    }

    if (h == 0) {
        const int c = t * 8;
        const float4 x0 = *(const float4*)(x + (size_t)n * CC + c);
        const float4 x1 = *(const float4*)(x + (size_t)n * CC + c + 4);
        const float4 b0 = *(const float4*)(bias + c);
        const float4 b1 = *(const float4*)(bias + c + 4);
        float4 o0, o1;
        o0.x = 0.8f * x0.x + 0.2f * (r0 + b0.x);
        o0.y = 0.8f * x0.y + 0.2f * (r1 + b0.y);
        o0.z = 0.8f * x0.z + 0.2f * (r2 + b0.z);
        o0.w = 0.8f * x0.w + 0.2f * (r3 + b0.w);
        o1.x = 0.8f * x1.x + 0.2f * (r4 + b1.x);
        o1.y = 0.8f * x1.y + 0.2f * (r5 + b1.y);
        o1.z = 0.8f * x1.z + 0.2f * (r6 + b1.z);
        o1.w = 0.8f * x1.w + 0.2f * (r7 + b1.w);
        *(float4*)(out + (size_t)n * CC + c)     = o0;
        *(float4*)(out + (size_t)n * CC + c + 4) = o1;
    }
}

extern "C" void kernel_launch(void* const* d_in, const int* in_sizes, int n_in,
                              void* d_out, int out_size, void* d_ws, size_t ws_size,
                              hipStream_t stream)
{
    const float* x     = (const float*)d_in[0];
    const int*   ei    = (const int*)d_in[1];
    const float* W     = (const float*)d_in[2];
    const float* att_s = (const float*)d_in[3];
    const float* att_d = (const float*)d_in[4];
    const float* bias  = (const float*)d_in[5];
    float* out = (float*)d_out;

    char* p = (char*)d_ws;
    unsigned char*  xhq   = (unsigned char*)p;  p += (size_t)NN * HCW;      // 25.6 MB
    unsigned short* wt    = (unsigned short*)p; p += (size_t)HCW * CC * 2;  // 128 KB
    float*          asrc  = (float*)p;          p += (size_t)NN * HH * 4;
    float*          adst  = (float*)p;          p += (size_t)NN * HH * 4;
    int*            deg   = (int*)p;            p += (size_t)NN * 4;        // zeroed
    unsigned short* pos   = (unsigned short*)p; p += (size_t)TOT * 2;
    int*            rowptr= (int*)p;            p += (size_t)(NN + 1) * 4;
    int*            csr_s = (int*)p;            p += (size_t)TOT * 4;
    int*            part  = (int*)p;            p += (size_t)SCAN_B * 4;

    hipMemsetAsync(deg, 0, (size_t)NN * 4, stream);

    k_prep_w<<<(HCW * CC + 255) / 256, 256, 0, stream>>>(W, wt);
    k_fat<<<CNTB + GEMB, 1024, 0, stream>>>(x, wt, att_s, att_d, ei, xhq, asrc, adst, deg, pos);
    s_part<<<SCAN_B, 256, 0, stream>>>(deg, part);
    s_apply<<<SCAN_B, 256, 0, stream>>>(deg, part, rowptr);
    k_scatter<<<(TOT + 255) / 256, 256, 0, stream>>>(ei, rowptr, pos, csr_s);
    {
        const long long threads = (long long)NN * 64;
        const int blocks = (int)((threads + 255) / 256);
        k_gather<<<blocks, 256, 0, stream>>>(rowptr, csr_s, asrc, adst, xhq, x, bias, out);
    }
}

// Round 17
// 154.773 us; speedup vs baseline: 1.1830x; 1.0652x over previous
//
#include <hip/hip_runtime.h>
#include <math.h>

#define NN 50000
#define EE 800000
#define TOT (EE + NN)          // 850000 edges incl. self loops
#define CC 128
#define HH 4
#define HCW 512                // H*C
#define SCAN_B 196             // ceil(NN/256)
#define RB 64                  // rows per gemm block
#define GEMB ((NN + RB - 1) / RB)        // 782 gemm blocks
#define EPB  ((TOT + GEMB - 1) / GEMB)   // 1087 edges per gemm block
#define LOG2E 1.442695040888963f

typedef short s16x8 __attribute__((ext_vector_type(8)));
typedef float f32x4 __attribute__((ext_vector_type(4)));
typedef float f32x2 __attribute__((ext_vector_type(2)));

// fp32 -> bf16 bits, round-to-nearest-even
__device__ __forceinline__ unsigned f2bf(float f) {
    unsigned u = __float_as_uint(f);
    return (u + 0x7fffu + ((u >> 16) & 1u)) >> 16;
}

// -------- P2: W [128][512] fp32 -> Wt [512][128] bf16 --------
__global__ __launch_bounds__(256) void k_prep_w(
    const float* __restrict__ W, unsigned short* __restrict__ wt)
{
    const int i = blockIdx.x * 256 + threadIdx.x;   // i = c*128 + k
    if (i >= HCW * CC) return;
    const int c = i >> 7, k = i & 127;
    wt[i] = (unsigned short)f2bf(W[(size_t)k * HCW + c]);
}

// -------- K1 (fat): every block = MFMA gemm tile + ~1087 count edges.
// The returning degree atomics are ISSUED in the prologue and their results
// consumed only in the epilogue -> their latency/fabric time hides under the
// gemm (r15/r16 showed separate count blocks merely concatenate: 75us at
// MfmaUtil 3.2%). --------
__global__ __launch_bounds__(1024, 4) void k_fat(
    const float* __restrict__ x,             // [NN][128] fp32
    const unsigned short* __restrict__ wt,   // [512][128] bf16 = W^T
    const float* __restrict__ att_s, const float* __restrict__ att_d,
    const int* __restrict__ ei,
    unsigned char* __restrict__ xhq,         // [NN][512] fp8 e4m3
    float* __restrict__ asrc, float* __restrict__ adst,
    int* __restrict__ deg, unsigned short* __restrict__ pos)
{
    __shared__ unsigned short xs[RB][CC + 8];   // 64x136 bf16
    __shared__ float red[16][2][4][16];         // [wave][src/dst][rt][row]

    const int tid = threadIdx.x;

    // ---- count prologue: issue returning atomics, consume at the end ----
    const int ebase = blockIdx.x * EPB;
    const int e0 = ebase + tid;
    const int e1 = ebase + 1024 + tid;
    const bool v0 = (e0 < TOT);                          // tid < 1024 < EPB
    const bool v1 = ((1024 + tid) < EPB) && (e1 < TOT);
    int old0 = 0, old1 = 0;
    if (v0) {
        const int d = (e0 < EE) ? ei[EE + e0] : (e0 - EE);
        old0 = atomicAdd(deg + d, 1);
    }
    if (v1) {
        const int d = (e1 < EE) ? ei[EE + e1] : (e1 - EE);
        old1 = atomicAdd(deg + d, 1);
    }

    // ---- gemm part ----
    const int r0   = blockIdx.x * RB;
    const int wv   = tid >> 6;               // 0..15
    const int lane = tid & 63;
    const int lrow = lane & 15;
    const int kg   = lane >> 4;
    const int n_base = wv * 32;              // 32 channels per wave
    const int h    = wv >> 2;                // head = n_base / 128

    // stage 64 rows of x as bf16 into LDS
    for (int i = tid; i < RB * 32; i += 1024) {
        const int row = i >> 5;
        const int c4  = (i & 31) * 4;
        const int grow = r0 + row;
        float4 v = make_float4(0.f, 0.f, 0.f, 0.f);
        if (grow < NN) v = *(const float4*)(x + (size_t)grow * CC + c4);
        uint2 o;
        o.x = f2bf(v.x) | (f2bf(v.y) << 16);
        o.y = f2bf(v.z) | (f2bf(v.w) << 16);
        *(uint2*)(&xs[row][c4]) = o;
    }

    // this wave's 8 wt fragments (2 channel-tiles x 4 k-chunks) stay in VGPRs
    s16x8 wf0[4], wf1[4];
#pragma unroll
    for (int kk = 0; kk < 4; ++kk) {
        wf0[kk] = *(const s16x8*)(wt + (size_t)(n_base + 0  + lrow) * CC + kg * 8 + kk * 32);
        wf1[kk] = *(const s16x8*)(wt + (size_t)(n_base + 16 + lrow) * CC + kg * 8 + kk * 32);
    }
    __syncthreads();

    const int cbase = h * CC + (wv & 3) * 32 + kg * 4;   // channel within head

    float psr[4], pdr[4];

    for (int rt = 0; rt < 4; ++rt) {
        f32x4 acc0 = {0.f, 0.f, 0.f, 0.f};
        f32x4 acc1 = {0.f, 0.f, 0.f, 0.f};
#pragma unroll
        for (int kk = 0; kk < 4; ++kk) {
            const s16x8 b = *(const s16x8*)(&xs[rt * 16 + lrow][kg * 8 + kk * 32]);
            acc0 = __builtin_amdgcn_mfma_f32_16x16x32_bf16(wf0[kk], b, acc0, 0, 0, 0);
            acc1 = __builtin_amdgcn_mfma_f32_16x16x32_bf16(wf1[kk], b, acc1, 0, 0, 0);
        }

        const int grow = r0 + rt * 16 + lrow;
        if (grow < NN) {
            unsigned char* orow = xhq + (size_t)grow * HCW + n_base + kg * 4;
            unsigned u;
            u = __builtin_amdgcn_cvt_pk_fp8_f32(acc0[0], acc0[1], 0u, false);
            u = __builtin_amdgcn_cvt_pk_fp8_f32(acc0[2], acc0[3], u, true);
            *(unsigned*)(orow) = u;
            u = __builtin_amdgcn_cvt_pk_fp8_f32(acc1[0], acc1[1], 0u, false);
            u = __builtin_amdgcn_cvt_pk_fp8_f32(acc1[2], acc1[3], u, true);
            *(unsigned*)(orow + 16) = u;
        }

        // fused a_src/a_dst epilogue (coeffs loaded in-loop: short live range)
        float ps, pd;
        {
            const float4 c0 = *(const float4*)(att_s + cbase);
            const float4 c1 = *(const float4*)(att_s + cbase + 16);
            ps = acc0[0]*c0.x + acc0[1]*c0.y + acc0[2]*c0.z + acc0[3]*c0.w
               + acc1[0]*c1.x + acc1[1]*c1.y + acc1[2]*c1.z + acc1[3]*c1.w;
        }
        {
            const float4 c0 = *(const float4*)(att_d + cbase);
            const float4 c1 = *(const float4*)(att_d + cbase + 16);
            pd = acc0[0]*c0.x + acc0[1]*c0.y + acc0[2]*c0.z + acc0[3]*c0.w
               + acc1[0]*c1.x + acc1[1]*c1.y + acc1[2]*c1.z + acc1[3]*c1.w;
        }
        ps += __shfl_xor(ps, 16); ps += __shfl_xor(ps, 32);
        pd += __shfl_xor(pd, 16); pd += __shfl_xor(pd, 32);
        psr[rt] = ps;
        pdr[rt] = pd;
    }

#pragma unroll
    for (int rt = 0; rt < 4; ++rt) {
        red[wv][0][rt][lrow] = psr[rt];   // kg groups write identical values
        red[wv][1][rt][lrow] = pdr[rt];
    }
    __syncthreads();                      // single barrier for the epilogue
    if (tid < 512) {
        const int t     = tid & 15;
        const int rt    = (tid >> 4) & 3;
        const int hh    = (tid >> 6) & 3;
        const int which = (tid >> 8) & 1;    // 0 = src, 1 = dst
        const int row   = r0 + rt * 16 + t;
        if (row < NN) {
            const float v = red[hh * 4 + 0][which][rt][t] + red[hh * 4 + 1][which][rt][t]
                          + red[hh * 4 + 2][which][rt][t] + red[hh * 4 + 3][which][rt][t];
            float* dst = which ? adst : asrc;
            dst[row * HH + hh] = v * LOG2E;   // pre-scale for exp2 in gather
        }
    }

    // ---- count epilogue: atomic returns have long since landed ----
    if (v0) pos[e0] = (unsigned short)old0;
    if (v1) pos[e1] = (unsigned short)old1;
}

// -------- scan: per-block partial sums --------
__global__ __launch_bounds__(256) void s_part(
    const int* __restrict__ deg, int* __restrict__ part)
{
    const int idx = blockIdx.x * 256 + threadIdx.x;
    int v = (idx < NN) ? deg[idx] : 0;
#pragma unroll
    for (int off = 1; off < 64; off <<= 1) v += __shfl_xor(v, off);
    __shared__ int sm[4];
    if ((threadIdx.x & 63) == 0) sm[threadIdx.x >> 6] = v;
    __syncthreads();
    if (threadIdx.x == 0) part[blockIdx.x] = sm[0] + sm[1] + sm[2] + sm[3];
}

// -------- scan apply (mid-scan inlined) --------
__global__ __launch_bounds__(256) void s_apply(
    const int* __restrict__ deg, const int* __restrict__ part,
    int* __restrict__ rowptr)
{
    __shared__ int sm[256];
    __shared__ int ws[4];
    const int t   = threadIdx.x;
    const int bid = blockIdx.x;

    int pv = (t < SCAN_B && t < bid) ? part[t] : 0;
#pragma unroll
    for (int off = 1; off < 64; off <<= 1) pv += __shfl_xor(pv, off);
    if ((t & 63) == 0) ws[t >> 6] = pv;
    __syncthreads();
    const int poff = ws[0] + ws[1] + ws[2] + ws[3];

    const int idx = bid * 256 + t;
    const int v = (idx < NN) ? deg[idx] : 0;
    sm[t] = v;
    __syncthreads();
    for (int off = 1; off < 256; off <<= 1) {
        int u = (t >= off) ? sm[t - off] : 0;
        __syncthreads();
        sm[t] += u;
        __syncthreads();
    }
    if (idx < NN) rowptr[idx] = poff + sm[t] - v;   // exclusive
    if (bid == 0 && t == 0) rowptr[NN] = TOT;
}

// -------- K4: atomic-free scatter of src ids into dst-sorted CSR --------
__global__ __launch_bounds__(256) void k_scatter(
    const int* __restrict__ ei, const int* __restrict__ rowptr,
    const unsigned short* __restrict__ pos, int* __restrict__ csr_s)
{
    const int e = blockIdx.x * 256 + threadIdx.x;
    if (e >= TOT) return;
    int s, d;
    if (e < EE) { s = ei[e]; d = ei[EE + e]; } else { s = d = e - EE; }
    csr_s[rowptr[d] + pos[e]] = s;
}

// -------- K5: single-pass softmax + fp8 gather + residual (r13 shape) ----
// one wave per node; lane = h*16 + t owns channels lane*8..+7.
// Edge ids / row bases wave-uniform -> readfirstlane to SGPR; per-lane
// asrc dword load; 8-deep main loop; predicated 4-wide tail.
__global__ __launch_bounds__(256) void k_gather(
    const int* __restrict__ rowptr, const int* __restrict__ csr_s,
    const float* __restrict__ asrc, const float* __restrict__ adst,
    const unsigned char* __restrict__ xhq, const float* __restrict__ x,
    const float* __restrict__ bias, float* __restrict__ out)
{
    const int gtid = blockIdx.x * 256 + threadIdx.x;
    const int n    = __builtin_amdgcn_readfirstlane(gtid >> 6);   // wave-uniform
    const int lane = threadIdx.x & 63;
    if (n >= NN) return;
    const int h = lane >> 4;
    const int t = lane & 15;

    const int beg = __builtin_amdgcn_readfirstlane(rowptr[n]);
    const int end = __builtin_amdgcn_readfirstlane(rowptr[n + 1]);
    const float ad = adst[n * HH + h];
    const int voff = lane << 3;            // byte offset within a 512B xh row

    float ssum = 0.f;
    f32x2 a0 = {0.f, 0.f}, a1 = {0.f, 0.f}, a2 = {0.f, 0.f}, a3 = {0.f, 0.f};

    int j = beg;
    // ---- exact 8-wide batches, scalar bases ----
    for (; j + 8 <= end; j += 8) {
        int ss[8];
#pragma unroll
        for (int u = 0; u < 8; ++u)
            ss[u] = __builtin_amdgcn_readfirstlane(csr_s[j + u]);
        uint2 qq[8];
#pragma unroll
        for (int u = 0; u < 8; ++u)
            qq[u] = *(const uint2*)(xhq + ((size_t)(unsigned)ss[u] << 9) + voff);
        float ww[8];
#pragma unroll
        for (int u = 0; u < 8; ++u) {
            float e = asrc[(ss[u] << 2) + h] + ad;
            e = fmaxf(e, 0.2f * e);        // leaky_relu, exact
            ww[u] = exp2f(e);
            ssum += ww[u];
        }
#pragma unroll
        for (int u = 0; u < 8; ++u) {
            const f32x2 p0 = __builtin_amdgcn_cvt_pk_f32_fp8(qq[u].x, false);
            const f32x2 p1 = __builtin_amdgcn_cvt_pk_f32_fp8(qq[u].x, true);
            const f32x2 p2 = __builtin_amdgcn_cvt_pk_f32_fp8(qq[u].y, false);
            const f32x2 p3 = __builtin_amdgcn_cvt_pk_f32_fp8(qq[u].y, true);
            const f32x2 wv = {ww[u], ww[u]};
            a0 += wv * p0; a1 += wv * p1; a2 += wv * p2; a3 += wv * p3;
        }
    }
    // ---- tail: up to two predicated 4-wide batches (indices still uniform) --
    for (int base = j; base < end; base += 4) {
        int ss[4];
#pragma unroll
        for (int u = 0; u < 4; ++u) {
            const int idx = (base + u < end) ? (base + u) : (end - 1);
            ss[u] = __builtin_amdgcn_readfirstlane(csr_s[idx]);
        }
        uint2 qq[4];
#pragma unroll
        for (int u = 0; u < 4; ++u)
            qq[u] = *(const uint2*)(xhq + ((size_t)(unsigned)ss[u] << 9) + voff);
        float ww[4];
#pragma unroll
        for (int u = 0; u < 4; ++u) {
            float e = asrc[(ss[u] << 2) + h] + ad;
            e = fmaxf(e, 0.2f * e);
            float w = exp2f(e);
            w = (base + u < end) ? w : 0.f;
            ww[u] = w;
            ssum += w;
        }
#pragma unroll
        for (int u = 0; u < 4; ++u) {
            const f32x2 p0 = __builtin_amdgcn_cvt_pk_f32_fp8(qq[u].x, false);
            const f32x2 p1 = __builtin_amdgcn_cvt_pk_f32_fp8(qq[u].x, true);
            const f32x2 p2 = __builtin_amdgcn_cvt_pk_f32_fp8(qq[u].y, false);
            const f32x2 p3 = __builtin_amdgcn_cvt_pk_f32_fp8(qq[u].y, true);
            const f32x2 wv = {ww[u], ww[u]};
            a0 += wv * p0; a1 += wv * p1; a2 += wv * p2; a3 += wv * p3;
        }
    }

    const float inv = 0.25f / (ssum + 1e-16f);
    const f32x2 iv = {inv, inv};
    a0 *= iv; a1 *= iv; a2 *= iv; a3 *= iv;
    float r0 = a0.x, r1 = a0.y, r2 = a1.x, r3 = a1.y;
    float r4 = a2.x, r5 = a2.y, r6 = a3.x, r7 = a3.y;

    // sum across the 4 head groups (lane bits 4..5)
#pragma unroll
    for (int off = 16; off < 64; off <<= 1) {
        r0 += __shfl_xor(r0, off); r1 += __shfl_xor(r1, off);
        r2 += __shfl_xor(r2, off); r3 += __shfl_xor(r3, off);
        r4 += __shfl_xor(r4, off); r5 += __shfl_xor(r5, off);
        r6 += __shfl_xor(r6, off); r7 += __shfl_xor(r7, off);
    }

    if (h == 0) {
        const int c = t * 8;
        const float4 x0 = *(const float4*)(x + (size_t)n * CC + c);
        const float4 x1 = *(const float4*)(x + (size_t)n * CC + c + 4);
        const float4 b0 = *(const float4*)(bias + c);
        const float4 b1 = *(const float4*)(bias + c + 4);
        float4 o0, o1;
        o0.x = 0.8f * x0.x + 0.2f * (r0 + b0.x);
        o0.y = 0.8f * x0.y + 0.2f * (r1 + b0.y);
        o0.z = 0.8f * x0.z + 0.2f * (r2 + b0.z);
        o0.w = 0.8f * x0.w + 0.2f * (r3 + b0.w);
        o1.x = 0.8f * x1.x + 0.2f * (r4 + b1.x);
        o1.y = 0.8f * x1.y + 0.2f * (r5 + b1.y);
        o1.z = 0.8f * x1.z + 0.2f * (r6 + b1.z);
        o1.w = 0.8f * x1.w + 0.2f * (r7 + b1.w);
        *(float4*)(out + (size_t)n * CC + c)     = o0;
        *(float4*)(out + (size_t)n * CC + c + 4) = o1;
    }
}

extern "C" void kernel_launch(void* const* d_in, const int* in_sizes, int n_in,
                              void* d_out, int out_size, void* d_ws, size_t ws_size,
                              hipStream_t stream)
{
    const float* x     = (const float*)d_in[0];
    const int*   ei    = (const int*)d_in[1];
    const float* W     = (const float*)d_in[2];
    const float* att_s = (const float*)d_in[3];
    const float* att_d = (const float*)d_in[4];
    const float* bias  = (const float*)d_in[5];
    float* out = (float*)d_out;

    char* p = (char*)d_ws;
    unsigned char*  xhq   = (unsigned char*)p;  p += (size_t)NN * HCW;      // 25.6 MB
    unsigned short* wt    = (unsigned short*)p; p += (size_t)HCW * CC * 2;  // 128 KB
    float*          asrc  = (float*)p;          p += (size_t)NN * HH * 4;
    float*          adst  = (float*)p;          p += (size_t)NN * HH * 4;
    int*            deg   = (int*)p;            p += (size_t)NN * 4;        // zeroed
    unsigned short* pos   = (unsigned short*)p; p += (size_t)TOT * 2;
    int*            rowptr= (int*)p;            p += (size_t)(NN + 1) * 4;
    int*            csr_s = (int*)p;            p += (size_t)TOT * 4;
    int*            part  = (int*)p;            p += (size_t)SCAN_B * 4;

    hipMemsetAsync(deg, 0, (size_t)NN * 4, stream);

    k_prep_w<<<(HCW * CC + 255) / 256, 256, 0, stream>>>(W, wt);
    k_fat<<<GEMB, 1024, 0, stream>>>(x, wt, att_s, att_d, ei, xhq, asrc, adst, deg, pos);
    s_part<<<SCAN_B, 256, 0, stream>>>(deg, part);
    s_apply<<<SCAN_B, 256, 0, stream>>>(deg, part, rowptr);
    k_scatter<<<(TOT + 255) / 256, 256, 0, stream>>>(ei, rowptr, pos, csr_s);
    {
        const long long threads = (long long)NN * 64;
        const int blocks = (int)((threads + 255) / 256);
        k_gather<<<blocks, 256, 0, stream>>>(rowptr, csr_s, asrc, adst, xhq, x, bias, out);
    }
}